// Round 7
// baseline (969.928 us; speedup 1.0000x reference)
//
#include <hip/hip_runtime.h>

#define NF 128
#define BIN_SHIFT 4
#define BIN_NODES 16
#define FB 64            // hist/fill partition blocks
#define IB 64            // bucket-init blocks
#define PADM 32          // bin slice padded to multiple of 32 edges
#define MAXBIN 2560
#define DUMMY 0x00100000u  // rel=16 (scratch row), src=0

// ---------- power iteration (blocks 0,1) + edge histogram (2..FB+1) + bucket init ----------
__global__ __launch_bounds__(512) void power_hist_kernel(
    const float* __restrict__ W1, const float* __restrict__ u1,
    const float* __restrict__ W2, const float* __restrict__ u2,
    const int* __restrict__ dst, int n_edges,
    int* __restrict__ hist2d, int nbin,
    unsigned int* __restrict__ bucket, int bucket_len4,
    float* __restrict__ inv_sigma, float* __restrict__ W1t,
    float* __restrict__ colzero) {
    __shared__ float Wl[128][129];
    __shared__ float us[128], vv[128], part[4][128], red[128];
    __shared__ int hist[MAXBIN];
    int tid = threadIdx.x;

    if (blockIdx.x >= 2 + FB) {  // bucket init with DUMMY
        int ib = blockIdx.x - 2 - FB;
        uint4* b4 = (uint4*)bucket;
        uint4 dv = make_uint4(DUMMY, DUMMY, DUMMY, DUMMY);
        for (int i = ib * 512 + tid; i < bucket_len4; i += IB * 512) b4[i] = dv;
        return;
    }
    if (blockIdx.x >= 2) {  // histogram chunk
        int fb = blockIdx.x - 2;
        for (int i = tid; i < nbin; i += 512) hist[i] = 0;
        __syncthreads();
        int chunk = (n_edges + FB - 1) / FB;
        int e0 = fb * chunk, e1 = min(e0 + chunk, n_edges);
        for (int e = e0 + tid; e < e1; e += 512)
            atomicAdd(&hist[dst[e] >> BIN_SHIFT], 1);
        __syncthreads();
        for (int i = tid; i < nbin; i += 512) hist2d[i * FB + fb] = hist[i];  // [bin][fb]
        return;
    }

    const float* W = blockIdx.x ? W2 : W1;
    const float* u = blockIdx.x ? u2 : u1;
    const float4* W4 = (const float4*)W;
    for (int j = tid; j < 4096; j += 512) {
        float4 w = W4[j];
        int r = j >> 5, c0 = (j & 31) << 2;
        Wl[r][c0] = w.x; Wl[r][c0 + 1] = w.y; Wl[r][c0 + 2] = w.z; Wl[r][c0 + 3] = w.w;
    }
    if (tid < 128) us[tid] = u[tid];
    if (blockIdx.x == 0 && tid >= 256 && tid < 512) colzero[tid - 256] = 0.f;
    __syncthreads();

    int c = tid & 127, sl = tid >> 7;
    float acc = 0.f;
#pragma unroll
    for (int j = 0; j < 32; ++j) acc = fmaf(Wl[sl * 32 + j][c], us[sl * 32 + j], acc);
    part[sl][c] = acc;
    __syncthreads();
    if (tid < 128) {
        float v = part[0][tid] + part[1][tid] + part[2][tid] + part[3][tid];
        vv[tid] = v;
        red[tid] = v * v;
    }
    __syncthreads();
    for (int s = 64; s > 0; s >>= 1) { if (tid < s) red[tid] += red[tid + s]; __syncthreads(); }
    float nv = sqrtf(red[0]) + 1e-12f;
    __syncthreads();
    if (tid < 128) vv[tid] = vv[tid] / nv;
    __syncthreads();

    float t = 0.f;
#pragma unroll
    for (int k = 0; k < 32; ++k) t = fmaf(Wl[c][sl * 32 + k], vv[sl * 32 + k], t);
    part[sl][c] = t;
    __syncthreads();
    if (tid < 128) {
        float tv = part[0][tid] + part[1][tid] + part[2][tid] + part[3][tid];
        red[tid] = tv * tv;
    }
    __syncthreads();
    for (int s = 64; s > 0; s >>= 1) { if (tid < s) red[tid] += red[tid + s]; __syncthreads(); }
    float tt = red[0];
    float is = (sqrtf(tt) + 1e-12f) / tt;
    if (tid == 0) inv_sigma[blockIdx.x] = is;
    if (blockIdx.x == 0) {
        for (int idx = tid; idx < 16384; idx += 512) {
            int k = idx >> 7, j = idx & 127;
            W1t[idx] = Wl[j][k] * is;
        }
    }
}

// ---------- scan: hist2d[bin][fb] -> per-(bin,fb) prefix; binOff = PADDED bin bases ----------
__global__ void scan2d_kernel(int* __restrict__ hist2d, int* __restrict__ binOff, int nbin) {
    __shared__ int sc[1024];
    int tid = threadIdx.x;
    int C = (nbin + 1023) >> 10;
    int b0 = tid * C, b1 = min(b0 + C, nbin);
    int tot = 0;
    for (int bin = b0; bin < b1; ++bin) {
        int run = 0;
        for (int fb = 0; fb < FB; ++fb) {          // contiguous per thread
            int v = hist2d[bin * FB + fb];
            hist2d[bin * FB + fb] = run;           // exclusive prefix within bin
            run += v;
        }
        binOff[bin] = tot;                         // local padded prefix (temp)
        tot += (run + PADM - 1) & ~(PADM - 1);     // pad to multiple of 32
    }
    sc[tid] = tot;
    __syncthreads();
    for (int off = 1; off < 1024; off <<= 1) {
        int v = (tid >= off) ? sc[tid - off] : 0;
        __syncthreads();
        sc[tid] += v;
        __syncthreads();
    }
    int excl = sc[tid] - tot;
    for (int bin = b0; bin < b1; ++bin) binOff[bin] += excl;
    if (tid == 1023) binOff[nbin] = sc[1023];
}

// ---------- fill: place edges into padded bins via LDS cursors ----------
__global__ __launch_bounds__(512) void fill_kernel(
    const int* __restrict__ src, const int* __restrict__ dst,
    const int* __restrict__ hist2d, const int* __restrict__ binOff,
    unsigned int* __restrict__ bucket, int nbin, int n_edges) {
    __shared__ int cur[MAXBIN];
    int tid = threadIdx.x;
    int fb = blockIdx.x;
    for (int i = tid; i < nbin; i += 512) cur[i] = hist2d[i * FB + fb] + binOff[i];
    __syncthreads();
    int chunk = (n_edges + FB - 1) / FB;
    int e0 = fb * chunk, e1 = min(e0 + chunk, n_edges);
    for (int e = e0 + tid; e < e1; e += 512) {
        int d = dst[e];
        int s = src[e];
        int pos = atomicAdd(&cur[d >> BIN_SHIFT], 1);
        bucket[pos] = ((unsigned)(d & (BIN_NODES - 1)) << 16) | (unsigned)s;
    }
}

// ---------- agg: branch-free ILP drain of one padded bin into 17-row LDS tile ----------
__global__ __launch_bounds__(512) void agg_kernel(
    const float* __restrict__ x, const unsigned int* __restrict__ bucket,
    const int* __restrict__ binOff, float* __restrict__ h0, int n_nodes) {
    __shared__ float hl[BIN_NODES + 1][128];  // row 16 = dummy scratch
    int tid = threadIdx.x;
    int node0 = blockIdx.x * BIN_NODES;

    const float4* x4 = (const float4*)x;
    for (int i = tid; i < BIN_NODES * 32; i += 512) {
        int r = i >> 5, c4 = i & 31;
        int gr = node0 + r;
        float4 v = (gr < n_nodes) ? x4[(size_t)gr * 32 + c4] : make_float4(0.f, 0.f, 0.f, 0.f);
        *(float4*)&hl[r][c4 << 2] = v;
    }
    __syncthreads();

    int lane = tid & 63, w = tid >> 6;  // 8 waves
    int start = binOff[blockIdx.x], end = binOff[blockIdx.x + 1];  // multiple-of-32 slice
    int j = start + w * 4;
    if (j < end) {
        uint4 e4 = *(const uint4*)&bucket[j];
        while (j < end) {
            int jn = j + PADM;
            uint4 nxt = make_uint4(DUMMY, DUMMY, DUMMY, DUMMY);
            if (jn < end) nxt = *(const uint4*)&bucket[jn];
            // 8 unconditional coalesced row loads (ILP), then fire-and-forget ds_add
            const float* r0 = &x[(size_t)(e4.x & 0xffffu) * NF];
            const float* r1 = &x[(size_t)(e4.y & 0xffffu) * NF];
            const float* r2 = &x[(size_t)(e4.z & 0xffffu) * NF];
            const float* r3 = &x[(size_t)(e4.w & 0xffffu) * NF];
            float a0 = r0[lane], b0 = r0[64 + lane];
            float a1 = r1[lane], b1 = r1[64 + lane];
            float a2 = r2[lane], b2 = r2[64 + lane];
            float a3 = r3[lane], b3 = r3[64 + lane];
            atomicAdd(&hl[e4.x >> 16][lane], a0);
            atomicAdd(&hl[e4.x >> 16][64 + lane], b0);
            atomicAdd(&hl[e4.y >> 16][lane], a1);
            atomicAdd(&hl[e4.y >> 16][64 + lane], b1);
            atomicAdd(&hl[e4.z >> 16][lane], a2);
            atomicAdd(&hl[e4.z >> 16][64 + lane], b2);
            atomicAdd(&hl[e4.w >> 16][lane], a3);
            atomicAdd(&hl[e4.w >> 16][64 + lane], b3);
            e4 = nxt;
            j = jn;
        }
    }
    __syncthreads();

    for (int i = tid; i < BIN_NODES * 32; i += 512) {
        int r = i >> 5, c4 = i & 31;
        int gr = node0 + r;
        if (gr < n_nodes)
            *(float4*)&h0[(size_t)gr * NF + (c4 << 2)] = *(const float4*)&hl[r][c4 << 2];
    }
}

// ---------- fallback: atomic scatter ----------
__global__ void edge_scatter_kernel(const int* __restrict__ ei, const float* __restrict__ x,
                                    float* __restrict__ h0, int n_edges) {
    int gtid = blockIdx.x * blockDim.x + threadIdx.x;
    int wid = gtid >> 6;
    int lane = threadIdx.x & 63;
    int nw = (gridDim.x * blockDim.x) >> 6;
    const int* srcs = ei;
    const int* dsts = ei + n_edges;
    for (int e = wid; e < n_edges; e += nw) {
        int s = srcs[e];
        int d = dsts[e];
        atomicAdd(&h0[d * NF + lane], x[s * NF + lane]);
        atomicAdd(&h0[d * NF + 64 + lane], x[s * NF + 64 + lane]);
    }
}

// ---------- GEMM: O = act(H @ Wt + bias); Wt [k][c] pre-transposed; BM=32, 512 thr --------
template <bool RELU, bool BNACC>
__global__ __launch_bounds__(512) void gemm32_kernel(
    const float* __restrict__ H, const float* __restrict__ Wt,
    const float* __restrict__ bias, float* __restrict__ O,
    float* __restrict__ colsum, float* __restrict__ colsumsq, int n_rows) {
    __shared__ float Hl[32][128];
    int tid = threadIdx.x;
    int m0 = blockIdx.x * 32;

    const float4* H4 = (const float4*)H;
    for (int j = tid; j < 1024; j += 512) {
        int r = j >> 5, c4 = j & 31;
        int gr = m0 + r;
        float4 h = (gr < n_rows) ? H4[(size_t)gr * 32 + c4] : make_float4(0.f, 0.f, 0.f, 0.f);
        *(float4*)&Hl[r][c4 << 2] = h;
    }
    __syncthreads();

    int tx = tid & 31, ty = tid >> 5;
    int rb = ty * 2, cb = tx * 4;
    float acc[2][4] = {};
    const float4* Wt4 = (const float4*)Wt;

    for (int k = 0; k < 128; k += 4) {
        float4 w0 = Wt4[((k + 0) << 5) + tx];
        float4 w1 = Wt4[((k + 1) << 5) + tx];
        float4 w2 = Wt4[((k + 2) << 5) + tx];
        float4 w3 = Wt4[((k + 3) << 5) + tx];
#pragma unroll
        for (int i = 0; i < 2; ++i) {
            float4 h = *(const float4*)&Hl[rb + i][k];
            acc[i][0] = fmaf(h.x, w0.x, acc[i][0]);
            acc[i][0] = fmaf(h.y, w1.x, acc[i][0]);
            acc[i][0] = fmaf(h.z, w2.x, acc[i][0]);
            acc[i][0] = fmaf(h.w, w3.x, acc[i][0]);
            acc[i][1] = fmaf(h.x, w0.y, acc[i][1]);
            acc[i][1] = fmaf(h.y, w1.y, acc[i][1]);
            acc[i][1] = fmaf(h.z, w2.y, acc[i][1]);
            acc[i][1] = fmaf(h.w, w3.y, acc[i][1]);
            acc[i][2] = fmaf(h.x, w0.z, acc[i][2]);
            acc[i][2] = fmaf(h.y, w1.z, acc[i][2]);
            acc[i][2] = fmaf(h.z, w2.z, acc[i][2]);
            acc[i][2] = fmaf(h.w, w3.z, acc[i][2]);
            acc[i][3] = fmaf(h.x, w0.w, acc[i][3]);
            acc[i][3] = fmaf(h.y, w1.w, acc[i][3]);
            acc[i][3] = fmaf(h.z, w2.w, acc[i][3]);
            acc[i][3] = fmaf(h.w, w3.w, acc[i][3]);
        }
    }

    float4 bv = *(const float4*)&bias[cb];
    float bvf[4] = {bv.x, bv.y, bv.z, bv.w};
    float s[4] = {0.f, 0.f, 0.f, 0.f}, qq[4] = {0.f, 0.f, 0.f, 0.f};
#pragma unroll
    for (int i = 0; i < 2; ++i) {
        int gr = m0 + rb + i;
        if (gr < n_rows) {
            float o[4];
#pragma unroll
            for (int j = 0; j < 4; ++j) {
                float v = acc[i][j] + bvf[j];
                if (RELU) v = fmaxf(v, 0.f);
                o[j] = v;
                if (BNACC) { s[j] += v; qq[j] = fmaf(v, v, qq[j]); }
            }
            *(float4*)&O[(size_t)gr * NF + cb] = make_float4(o[0], o[1], o[2], o[3]);
        }
    }

    if (BNACC) {
        __syncthreads();
        float* sS = &Hl[0][0];
        float* sQ = &Hl[16][0];
#pragma unroll
        for (int j = 0; j < 4; ++j) {
            sS[ty * 128 + cb + j] = s[j];
            sQ[ty * 128 + cb + j] = qq[j];
        }
        __syncthreads();
        if (tid < 128) {
            float ts = 0.f, tq = 0.f;
#pragma unroll
            for (int g = 0; g < 16; ++g) {
                ts += sS[g * 128 + tid];
                tq += sQ[g * 128 + tid];
            }
            atomicAdd(&colsum[tid], ts);
            atomicAdd(&colsumsq[tid], tq);
        }
    }
}

// ---------- fold BN into W2', emit TRANSPOSED W2pt[k][j], b2p ----------
__global__ void fold_kernel(const float* __restrict__ W2, const float* __restrict__ b2,
                            const float* __restrict__ gamma, const float* __restrict__ beta,
                            const float* __restrict__ colsum, const float* __restrict__ colsumsq,
                            const float* __restrict__ inv_sigma, float* __restrict__ W2pt,
                            float* __restrict__ b2p, float inv_n) {
    __shared__ float a[128], cc[128], red[128];
    int k = threadIdx.x;
    int j = blockIdx.x;
    float mu = colsum[k] * inv_n;
    float var = colsumsq[k] * inv_n - mu * mu;
    float ai = gamma[k] / sqrtf(var + 1e-5f);
    a[k] = ai;
    cc[k] = beta[k] - ai * mu;
    __syncthreads();
    float is2 = inv_sigma[1];
    float wv = W2[j * 128 + k] * is2;
    W2pt[k * 128 + j] = wv * a[k];
    red[k] = wv * cc[k];
    __syncthreads();
    for (int s = 64; s > 0; s >>= 1) { if (k < s) red[k] += red[k + s]; __syncthreads(); }
    if (k == 0) b2p[j] = b2[j] + red[0];
}

extern "C" void kernel_launch(void* const* d_in, const int* in_sizes, int n_in,
                              void* d_out, int out_size, void* d_ws, size_t ws_size,
                              hipStream_t stream) {
    const float* x     = (const float*)d_in[0];
    const int*   ei    = (const int*)d_in[1];
    const float* W1    = (const float*)d_in[2];
    const float* b1    = (const float*)d_in[3];
    const float* u1    = (const float*)d_in[4];
    const float* gamma = (const float*)d_in[5];
    const float* beta  = (const float*)d_in[6];
    const float* W2    = (const float*)d_in[7];
    const float* b2    = (const float*)d_in[8];
    const float* u2    = (const float*)d_in[9];
    float* out = (float*)d_out;

    int n_nodes = in_sizes[0] / NF;
    int n_edges = in_sizes[1] / 2;
    int nbin = (n_nodes + BIN_NODES - 1) / BIN_NODES;
    int bucket_len = n_edges + PADM * nbin;
    int bucket_len4 = (bucket_len + 3) >> 2;    // uint4 count
    bucket_len = bucket_len4 << 2;

    float* ws        = (float*)d_ws;
    float* inv_sigma = ws;                // 4
    float* colsum    = ws + 4;            // 128
    float* colsumsq  = colsum + 128;      // 128
    float* W1t       = colsumsq + 128;    // 16384
    float* W2pt      = W1t + 16384;       // 16384
    float* b2p       = W2pt + 16384;      // 128
    int*   binOff    = (int*)(b2p + 128);                       // nbin+1
    unsigned int* bucket = (unsigned int*)(binOff + nbin + 1);  // bucket_len
    float* h0        = (float*)(bucket + bucket_len);           // n_nodes*128
    int*   hist2d    = (int*)h0;                                // nbin*FB (dead before h0)

    size_t fixed = (4 + 256 + 2 * 16384 + 128) * sizeof(float);
    size_t fused_need = fixed + ((size_t)nbin + 1 + bucket_len) * sizeof(int)
                      + ((size_t)n_nodes * NF) * sizeof(float);
    bool fused = (nbin <= MAXBIN) && (n_nodes <= 65536) && (ws_size >= fused_need)
               && ((size_t)nbin * FB <= (size_t)n_nodes * NF);

    if (fused) {
        power_hist_kernel<<<2 + FB + IB, 512, 0, stream>>>(
            W1, u1, W2, u2, ei + n_edges, n_edges, hist2d, nbin,
            bucket, bucket_len4, inv_sigma, W1t, colsum);
        scan2d_kernel<<<1, 1024, 0, stream>>>(hist2d, binOff, nbin);
        fill_kernel<<<FB, 512, 0, stream>>>(ei, ei + n_edges, hist2d, binOff, bucket,
                                            nbin, n_edges);
        agg_kernel<<<nbin, 512, 0, stream>>>(x, bucket, binOff, h0, n_nodes);
    } else {
        power_hist_kernel<<<2, 512, 0, stream>>>(
            W1, u1, W2, u2, ei + n_edges, n_edges, nullptr, nbin,
            nullptr, 0, inv_sigma, W1t, colsum);
        hipMemcpyAsync(h0, x, (size_t)n_nodes * NF * sizeof(float),
                       hipMemcpyDeviceToDevice, stream);
        edge_scatter_kernel<<<2048, 256, 0, stream>>>(ei, x, h0, n_edges);
    }

    gemm32_kernel<true, true><<<(n_nodes + 31) / 32, 512, 0, stream>>>(
        h0, W1t, b1, out, colsum, colsumsq, n_nodes);

    fold_kernel<<<128, 128, 0, stream>>>(W2, b2, gamma, beta, colsum, colsumsq,
                                         inv_sigma, W2pt, b2p, 1.0f / (float)n_nodes);

    gemm32_kernel<false, false><<<(n_nodes + 31) / 32, 512, 0, stream>>>(
        out, W2pt, b2p, out, nullptr, nullptr, n_nodes);
}

// Round 8
// 131.389 us; speedup vs baseline: 7.3821x; 7.3821x over previous
//
#include <hip/hip_runtime.h>

#define NF 128
#define FB 64            // hist/fill partition chunks
#define MAXNODE 10240    // LDS cursor capacity (ints) -> fused path needs n_nodes <= 10240

// ---------- power iteration: inv_sigma[b], W1t (block 0), zero colsum ----------
__global__ __launch_bounds__(512) void power_iter_kernel(
    const float* __restrict__ W1, const float* __restrict__ u1,
    const float* __restrict__ W2, const float* __restrict__ u2,
    float* __restrict__ inv_sigma, float* __restrict__ W1t,
    float* __restrict__ colzero) {
    __shared__ float Wl[128][129];
    __shared__ float us[128], vv[128], part[4][128], red[128];
    int tid = threadIdx.x;

    const float* W = blockIdx.x ? W2 : W1;
    const float* u = blockIdx.x ? u2 : u1;
    const float4* W4 = (const float4*)W;
    for (int j = tid; j < 4096; j += 512) {
        float4 w = W4[j];
        int r = j >> 5, c0 = (j & 31) << 2;
        Wl[r][c0] = w.x; Wl[r][c0 + 1] = w.y; Wl[r][c0 + 2] = w.z; Wl[r][c0 + 3] = w.w;
    }
    if (tid < 128) us[tid] = u[tid];
    if (blockIdx.x == 0 && tid >= 256 && tid < 512) colzero[tid - 256] = 0.f;
    __syncthreads();

    int c = tid & 127, sl = tid >> 7;
    float acc = 0.f;
#pragma unroll
    for (int j = 0; j < 32; ++j) acc = fmaf(Wl[sl * 32 + j][c], us[sl * 32 + j], acc);
    part[sl][c] = acc;
    __syncthreads();
    if (tid < 128) {
        float v = part[0][tid] + part[1][tid] + part[2][tid] + part[3][tid];
        vv[tid] = v;
        red[tid] = v * v;
    }
    __syncthreads();
    for (int s = 64; s > 0; s >>= 1) { if (tid < s) red[tid] += red[tid + s]; __syncthreads(); }
    float nv = sqrtf(red[0]) + 1e-12f;
    __syncthreads();
    if (tid < 128) vv[tid] = vv[tid] / nv;
    __syncthreads();

    float t = 0.f;
#pragma unroll
    for (int k = 0; k < 32; ++k) t = fmaf(Wl[c][sl * 32 + k], vv[sl * 32 + k], t);
    part[sl][c] = t;
    __syncthreads();
    if (tid < 128) {
        float tv = part[0][tid] + part[1][tid] + part[2][tid] + part[3][tid];
        red[tid] = tv * tv;
    }
    __syncthreads();
    for (int s = 64; s > 0; s >>= 1) { if (tid < s) red[tid] += red[tid + s]; __syncthreads(); }
    float tt = red[0];
    float is = (sqrtf(tt) + 1e-12f) / tt;
    if (tid == 0) inv_sigma[blockIdx.x] = is;
    if (blockIdx.x == 0) {
        for (int idx = tid; idx < 16384; idx += 512) {
            int k = idx >> 7, j = idx & 127;
            W1t[idx] = Wl[j][k] * is;  // W1t[k][j], conflict-free (consecutive tid -> j)
        }
    }
}

// ---------- hist: per-chunk LDS node histogram -> hist2d[fb][node] ----------
__global__ __launch_bounds__(512) void hist_kernel(const int* __restrict__ dst, int n_edges,
                                                   int* __restrict__ hist2d, int nbin) {
    __shared__ int hist[MAXNODE];
    int tid = threadIdx.x, fb = blockIdx.x;
    for (int i = tid; i < nbin; i += 512) hist[i] = 0;
    __syncthreads();
    int chunk = (n_edges + FB - 1) / FB;
    int e0 = fb * chunk, e1 = min(e0 + chunk, n_edges);
    for (int e = e0 + tid; e < e1; e += 512) atomicAdd(&hist[dst[e]], 1);
    __syncthreads();
    for (int i = tid; i < nbin; i += 512) hist2d[(size_t)fb * nbin + i] = hist[i];
}

// ---------- scanA: thread-per-node, prefix over fb in place; binOff[n] = node total ----------
__global__ void scanA_kernel(int* __restrict__ hist2d, int* __restrict__ binOff, int nbin) {
    int bin = blockIdx.x * 1024 + threadIdx.x;
    if (bin >= nbin) return;
    int run = 0;
#pragma unroll 4
    for (int fb = 0; fb < FB; ++fb) {
        int v = hist2d[(size_t)fb * nbin + bin];  // coalesced across threads
        hist2d[(size_t)fb * nbin + bin] = run;
        run += v;
    }
    binOff[bin] = run;
}

// ---------- scanB: 1-block in-place exclusive scan of binOff; binOff[nbin] = total ----------
__global__ void scanB_kernel(int* __restrict__ binOff, int nbin) {
    __shared__ int sc[1024];
    int tid = threadIdx.x;
    int C = (nbin + 1023) >> 10;  // <= 16 guarded by launch
    int b0 = tid * C, b1 = min(b0 + C, nbin);
    int loc[16];
    int s = 0;
    for (int i = b0; i < b1; ++i) { loc[i - b0] = binOff[i]; s += loc[i - b0]; }
    sc[tid] = s;
    __syncthreads();
    for (int off = 1; off < 1024; off <<= 1) {
        int v = (tid >= off) ? sc[tid - off] : 0;
        __syncthreads();
        sc[tid] += v;
        __syncthreads();
    }
    int base = sc[tid] - s;
    for (int i = b0; i < b1; ++i) { binOff[i] = base; base += loc[i - b0]; }
    if (tid == 1023) binOff[nbin] = sc[1023];
}

// ---------- fill: LDS cursors (no global atomics), scatter src ids into node buckets ----------
__global__ __launch_bounds__(512) void fill_kernel(
    const int* __restrict__ src, const int* __restrict__ dst,
    const int* __restrict__ hist2d, const int* __restrict__ binOff,
    int* __restrict__ bucket, int nbin, int n_edges) {
    __shared__ int cur[MAXNODE];
    int tid = threadIdx.x, fb = blockIdx.x;
    for (int i = tid; i < nbin; i += 512)
        cur[i] = hist2d[(size_t)fb * nbin + i] + binOff[i];
    __syncthreads();
    int chunk = (n_edges + FB - 1) / FB;
    int e0 = fb * chunk, e1 = min(e0 + chunk, n_edges);
    for (int e = e0 + tid; e < e1; e += 512) {
        int d = dst[e];
        int s = src[e];
        int pos = atomicAdd(&cur[d], 1);  // LDS atomic, ~70cy
        bucket[pos] = s;                  // fire-and-forget scattered 4B
    }
}

// ---------- gather: wave-per-node, 4-edge ILP; h0[n] = x[n] + sum x[src] ----------
__global__ __launch_bounds__(256) void gather_kernel(
    const float* __restrict__ x, const int* __restrict__ bucket,
    const int* __restrict__ binOff, float* __restrict__ h0, int n_nodes) {
    int gw = (blockIdx.x * blockDim.x + threadIdx.x) >> 6;
    int lane = threadIdx.x & 63;
    if (gw >= n_nodes) return;
    const float2* x2 = (const float2*)x;
    float2 acc = x2[(size_t)gw * 64 + lane];
    int j = binOff[gw], end = binOff[gw + 1];
    for (; j + 4 <= end; j += 4) {
        int s0 = bucket[j], s1 = bucket[j + 1], s2 = bucket[j + 2], s3 = bucket[j + 3];
        float2 v0 = x2[(size_t)s0 * 64 + lane];
        float2 v1 = x2[(size_t)s1 * 64 + lane];
        float2 v2 = x2[(size_t)s2 * 64 + lane];
        float2 v3 = x2[(size_t)s3 * 64 + lane];
        acc.x += v0.x + v1.x + v2.x + v3.x;
        acc.y += v0.y + v1.y + v2.y + v3.y;
    }
    for (; j < end; ++j) {
        int s = bucket[j];
        float2 v = x2[(size_t)s * 64 + lane];
        acc.x += v.x;
        acc.y += v.y;
    }
    ((float2*)h0)[(size_t)gw * 64 + lane] = acc;
}

// ---------- fallback: atomic scatter ----------
__global__ void edge_scatter_kernel(const int* __restrict__ ei, const float* __restrict__ x,
                                    float* __restrict__ h0, int n_edges) {
    int gtid = blockIdx.x * blockDim.x + threadIdx.x;
    int wid = gtid >> 6;
    int lane = threadIdx.x & 63;
    int nw = (gridDim.x * blockDim.x) >> 6;
    const int* srcs = ei;
    const int* dsts = ei + n_edges;
    for (int e = wid; e < n_edges; e += nw) {
        int s = srcs[e];
        int d = dsts[e];
        atomicAdd(&h0[d * NF + lane], x[s * NF + lane]);
        atomicAdd(&h0[d * NF + 64 + lane], x[s * NF + 64 + lane]);
    }
}

// ---------- tiled GEMM (R3-proven): O = act(H @ Wt + bias), Wt pre-transposed [k][c] ----------
// BM=64, BN=128, 256 threads; thread (ty,tx): rows ty*8..+7, cols tx*4..+3.
template <bool RELU, bool BNACC>
__global__ __launch_bounds__(256, 1) void gemm_tiled_kernel(
    const float* __restrict__ H, const float* __restrict__ Wt,
    const float* __restrict__ bias, float* __restrict__ O,
    float* __restrict__ colsum, float* __restrict__ colsumsq, int n_rows) {
    __shared__ float Hl[64][128];
    __shared__ float Wl[128][132];
    int tid = threadIdx.x;
    int m0 = blockIdx.x * 64;

    const float4* Wt4 = (const float4*)Wt;
    for (int j = tid; j < 4096; j += 256) {
        int k = j >> 5, c4 = (j & 31) << 2;
        float4 w = Wt4[j];
        *(float4*)&Wl[k][c4] = w;
    }
    const float4* H4 = (const float4*)H;
    for (int j = tid; j < 2048; j += 256) {
        int r = j >> 5, k4 = j & 31;
        int gr = m0 + r;
        float4 h = (gr < n_rows) ? H4[(size_t)gr * 32 + k4] : make_float4(0.f, 0.f, 0.f, 0.f);
        *(float4*)&Hl[r][k4 << 2] = h;
    }
    __syncthreads();

    int tx = tid & 31, ty = tid >> 5;
    int rb = ty * 8, cb = tx * 4;
    float acc[8][4] = {};

    for (int k = 0; k < 128; k += 4) {
        float wv[4][4];
#pragma unroll
        for (int kk = 0; kk < 4; ++kk) {
            float4 t = *(const float4*)&Wl[k + kk][cb];
            wv[kk][0] = t.x; wv[kk][1] = t.y; wv[kk][2] = t.z; wv[kk][3] = t.w;
        }
#pragma unroll
        for (int i = 0; i < 8; ++i) {
            float4 h = *(const float4*)&Hl[rb + i][k];
            float hf[4] = {h.x, h.y, h.z, h.w};
#pragma unroll
            for (int kk = 0; kk < 4; ++kk)
#pragma unroll
                for (int j = 0; j < 4; ++j)
                    acc[i][j] = fmaf(hf[kk], wv[kk][j], acc[i][j]);
        }
    }

    float bv[4];
#pragma unroll
    for (int j = 0; j < 4; ++j) bv[j] = bias[cb + j];

    float s[4] = {0.f, 0.f, 0.f, 0.f}, q[4] = {0.f, 0.f, 0.f, 0.f};
#pragma unroll
    for (int i = 0; i < 8; ++i) {
        int gr = m0 + rb + i;
        if (gr < n_rows) {
            float o[4];
#pragma unroll
            for (int j = 0; j < 4; ++j) {
                float v = acc[i][j] + bv[j];
                if (RELU) v = fmaxf(v, 0.f);
                o[j] = v;
                if (BNACC) { s[j] += v; q[j] = fmaf(v, v, q[j]); }
            }
            *(float4*)&O[(size_t)gr * NF + cb] = make_float4(o[0], o[1], o[2], o[3]);
        }
    }

    if (BNACC) {
        __syncthreads();
        float* sS = &Hl[0][0];
        float* sQ = &Hl[16][0];
#pragma unroll
        for (int j = 0; j < 4; ++j) {
            sS[ty * 128 + cb + j] = s[j];
            sQ[ty * 128 + cb + j] = q[j];
        }
        __syncthreads();
        if (tid < 128) {
            float ts = 0.f, tq = 0.f;
#pragma unroll
            for (int g = 0; g < 8; ++g) {
                ts += sS[g * 128 + tid];
                tq += sQ[g * 128 + tid];
            }
            atomicAdd(&colsum[tid], ts);
            atomicAdd(&colsumsq[tid], tq);
        }
    }
}

// ---------- fold BN into W2', emit TRANSPOSED W2pt[k][j], b2p ----------
__global__ void fold_kernel(const float* __restrict__ W2, const float* __restrict__ b2,
                            const float* __restrict__ gamma, const float* __restrict__ beta,
                            const float* __restrict__ colsum, const float* __restrict__ colsumsq,
                            const float* __restrict__ inv_sigma, float* __restrict__ W2pt,
                            float* __restrict__ b2p, float inv_n) {
    __shared__ float a[128], cc[128], red[128];
    int k = threadIdx.x;
    int j = blockIdx.x;
    float mu = colsum[k] * inv_n;
    float var = colsumsq[k] * inv_n - mu * mu;
    float ai = gamma[k] / sqrtf(var + 1e-5f);
    a[k] = ai;
    cc[k] = beta[k] - ai * mu;
    __syncthreads();
    float is2 = inv_sigma[1];
    float wv = W2[j * 128 + k] * is2;
    W2pt[k * 128 + j] = wv * a[k];
    red[k] = wv * cc[k];
    __syncthreads();
    for (int s = 64; s > 0; s >>= 1) { if (k < s) red[k] += red[k + s]; __syncthreads(); }
    if (k == 0) b2p[j] = b2[j] + red[0];
}

extern "C" void kernel_launch(void* const* d_in, const int* in_sizes, int n_in,
                              void* d_out, int out_size, void* d_ws, size_t ws_size,
                              hipStream_t stream) {
    const float* x     = (const float*)d_in[0];
    const int*   ei    = (const int*)d_in[1];
    const float* W1    = (const float*)d_in[2];
    const float* b1    = (const float*)d_in[3];
    const float* u1    = (const float*)d_in[4];
    const float* gamma = (const float*)d_in[5];
    const float* beta  = (const float*)d_in[6];
    const float* W2    = (const float*)d_in[7];
    const float* b2    = (const float*)d_in[8];
    const float* u2    = (const float*)d_in[9];
    float* out = (float*)d_out;

    int n_nodes = in_sizes[0] / NF;
    int n_edges = in_sizes[1] / 2;
    int nbin = n_nodes;  // bin == node

    float* ws        = (float*)d_ws;
    float* inv_sigma = ws;                // 4
    float* colsum    = ws + 4;            // 128
    float* colsumsq  = colsum + 128;      // 128
    float* W1t       = colsumsq + 128;    // 16384
    float* W2pt      = W1t + 16384;       // 16384
    float* b2p       = W2pt + 16384;      // 128
    int*   binOff    = (int*)(b2p + 128);              // nbin+1
    int*   bucket    = binOff + nbin + 1;              // n_edges
    float* h0        = (float*)(bucket + n_edges);     // n_nodes*128
    int*   hist2d    = (int*)h0;                       // FB*nbin (dead before gather writes h0)

    size_t fixed = (4 + 256 + 2 * 16384 + 128) * sizeof(float);
    size_t need  = fixed + ((size_t)nbin + 1 + n_edges) * sizeof(int)
                 + (size_t)n_nodes * NF * sizeof(float);
    bool fused = (n_nodes <= MAXNODE) && (ws_size >= need)
               && ((size_t)FB * nbin <= (size_t)n_nodes * NF);

    // power iteration (2 blocks); zeros colsum/colsumsq; emits W1t
    power_iter_kernel<<<2, 512, 0, stream>>>(W1, u1, W2, u2, inv_sigma, W1t, colsum);

    if (fused) {
        hist_kernel<<<FB, 512, 0, stream>>>(ei + n_edges, n_edges, hist2d, nbin);
        scanA_kernel<<<(nbin + 1023) / 1024, 1024, 0, stream>>>(hist2d, binOff, nbin);
        scanB_kernel<<<1, 1024, 0, stream>>>(binOff, nbin);
        fill_kernel<<<FB, 512, 0, stream>>>(ei, ei + n_edges, hist2d, binOff, bucket,
                                            nbin, n_edges);
        gather_kernel<<<(n_nodes * 64 + 255) / 256, 256, 0, stream>>>(
            x, bucket, binOff, h0, n_nodes);
    } else {
        hipMemcpyAsync(h0, x, (size_t)n_nodes * NF * sizeof(float),
                       hipMemcpyDeviceToDevice, stream);
        edge_scatter_kernel<<<2048, 256, 0, stream>>>(ei, x, h0, n_edges);
    }

    int gemm_blocks = (n_nodes + 63) / 64;

    // h1 = relu(h0 @ W1sn^T + b1) -> d_out, fused BN col stats
    gemm_tiled_kernel<true, true><<<gemm_blocks, 256, 0, stream>>>(
        h0, W1t, b1, out, colsum, colsumsq, n_nodes);

    fold_kernel<<<128, 128, 0, stream>>>(W2, b2, gamma, beta, colsum, colsumsq,
                                         inv_sigma, W2pt, b2p, 1.0f / (float)n_nodes);

    // out = h1 @ W2p^T + b2p  (in-place: block reads only its own tile rows)
    gemm_tiled_kernel<false, false><<<gemm_blocks, 256, 0, stream>>>(
        out, W2pt, b2p, out, nullptr, nullptr, n_nodes);
}

// Round 9
// 126.168 us; speedup vs baseline: 7.6876x; 1.0414x over previous
//
#include <hip/hip_runtime.h>

#define NF 128
#define FB 128           // hist/fill partition chunks
#define MAXNODE 10240    // LDS cursor capacity (ints)

// ---------- power iteration (blocks 0,1) + per-chunk node histogram (blocks 2..FB+1) ----------
__global__ __launch_bounds__(512) void power_hist_kernel(
    const float* __restrict__ W1, const float* __restrict__ u1,
    const float* __restrict__ W2, const float* __restrict__ u2,
    const int* __restrict__ dst, int n_edges,
    int* __restrict__ hist2d, int nbin,
    float* __restrict__ inv_sigma, float* __restrict__ W1t,
    float* __restrict__ colzero) {
    __shared__ float Wl[128][129];
    __shared__ float us[128], vv[128], part[4][128], red[128];
    __shared__ int hist[MAXNODE];
    int tid = threadIdx.x;

    if (blockIdx.x >= 2) {  // histogram chunk
        int fb = blockIdx.x - 2;
        for (int i = tid; i < nbin; i += 512) hist[i] = 0;
        __syncthreads();
        int chunk = (n_edges + FB - 1) / FB;
        int e0 = fb * chunk, e1 = min(e0 + chunk, n_edges);
        int a0 = min(e1, (e0 + 3) & ~3);
        for (int e = e0 + tid; e < a0; e += 512) atomicAdd(&hist[dst[e]], 1);
        const int4* d4 = (const int4*)dst;
        int vs = a0 >> 2, ve = e1 >> 2;
        for (int i = vs + tid; i < ve; i += 512) {
            int4 d = d4[i];
            atomicAdd(&hist[d.x], 1);
            atomicAdd(&hist[d.y], 1);
            atomicAdd(&hist[d.z], 1);
            atomicAdd(&hist[d.w], 1);
        }
        for (int e = (ve << 2) + tid; e < e1; e += 512)
            if (e >= a0) atomicAdd(&hist[dst[e]], 1);
        __syncthreads();
        for (int i = tid; i < nbin; i += 512) hist2d[(size_t)fb * nbin + i] = hist[i];
        return;
    }

    const float* W = blockIdx.x ? W2 : W1;
    const float* u = blockIdx.x ? u2 : u1;
    const float4* W4 = (const float4*)W;
    for (int j = tid; j < 4096; j += 512) {
        float4 w = W4[j];
        int r = j >> 5, c0 = (j & 31) << 2;
        Wl[r][c0] = w.x; Wl[r][c0 + 1] = w.y; Wl[r][c0 + 2] = w.z; Wl[r][c0 + 3] = w.w;
    }
    if (tid < 128) us[tid] = u[tid];
    if (blockIdx.x == 0 && tid >= 256 && tid < 512) colzero[tid - 256] = 0.f;
    __syncthreads();

    int c = tid & 127, sl = tid >> 7;
    float acc = 0.f;
#pragma unroll
    for (int j = 0; j < 32; ++j) acc = fmaf(Wl[sl * 32 + j][c], us[sl * 32 + j], acc);
    part[sl][c] = acc;
    __syncthreads();
    if (tid < 128) {
        float v = part[0][tid] + part[1][tid] + part[2][tid] + part[3][tid];
        vv[tid] = v;
        red[tid] = v * v;
    }
    __syncthreads();
    for (int s = 64; s > 0; s >>= 1) { if (tid < s) red[tid] += red[tid + s]; __syncthreads(); }
    float nv = sqrtf(red[0]) + 1e-12f;
    __syncthreads();
    if (tid < 128) vv[tid] = vv[tid] / nv;
    __syncthreads();

    float t = 0.f;
#pragma unroll
    for (int k = 0; k < 32; ++k) t = fmaf(Wl[c][sl * 32 + k], vv[sl * 32 + k], t);
    part[sl][c] = t;
    __syncthreads();
    if (tid < 128) {
        float tv = part[0][tid] + part[1][tid] + part[2][tid] + part[3][tid];
        red[tid] = tv * tv;
    }
    __syncthreads();
    for (int s = 64; s > 0; s >>= 1) { if (tid < s) red[tid] += red[tid + s]; __syncthreads(); }
    float tt = red[0];
    float is = (sqrtf(tt) + 1e-12f) / tt;
    if (tid == 0) inv_sigma[blockIdx.x] = is;
    if (blockIdx.x == 0) {
        for (int idx = tid; idx < 16384; idx += 512) {
            int k = idx >> 7, j = idx & 127;
            W1t[idx] = Wl[j][k] * is;  // W1t[k][j]
        }
    }
}

// ---------- scanA: thread-per-node, exclusive prefix over fb in place; binOff[n] = node total ----
__global__ void scanA_kernel(int* __restrict__ hist2d, int* __restrict__ binOff, int nbin) {
    int bin = blockIdx.x * 1024 + threadIdx.x;
    if (bin >= nbin) return;
    int run = 0;
#pragma unroll 4
    for (int fb = 0; fb < FB; ++fb) {
        int v = hist2d[(size_t)fb * nbin + bin];  // coalesced across threads
        hist2d[(size_t)fb * nbin + bin] = run;
        run += v;
    }
    binOff[bin] = run;
}

// ---------- scanB: shuffle-based tiled exclusive scan of binOff; binOff[nbin] = total ----------
__global__ __launch_bounds__(1024) void scanB_kernel(int* __restrict__ binOff, int nbin) {
    __shared__ int wsum[16], wexcl[16];
    __shared__ int carry_s;
    int tid = threadIdx.x, lane = tid & 63, wv = tid >> 6;
    if (tid == 0) carry_s = 0;
    __syncthreads();
    int nr = (nbin + 1023) >> 10;
    for (int r = 0; r < nr; ++r) {
        int i = (r << 10) + tid;
        int v = (i < nbin) ? binOff[i] : 0;
        int inc = v;
        for (int off = 1; off < 64; off <<= 1) {
            int t = __shfl_up(inc, off);
            if (lane >= off) inc += t;
        }
        if (lane == 63) wsum[wv] = inc;
        __syncthreads();
        if (wv == 0) {
            int s = (lane < 16) ? wsum[lane] : 0;
            int si = s;
            for (int off = 1; off < 16; off <<= 1) {
                int t = __shfl_up(si, off);
                if (lane >= off) si += t;
            }
            if (lane < 16) wexcl[lane] = si - s;
        }
        __syncthreads();
        int excl = inc - v + wexcl[wv] + carry_s;
        if (i < nbin) binOff[i] = excl;
        __syncthreads();
        if (tid == 1023) carry_s += wexcl[15] + wsum[15];
        __syncthreads();
    }
    if (threadIdx.x == 0) binOff[nbin] = carry_s;
}

// ---------- fill: LDS cursors (no global atomics), scatter src ids into node buckets ----------
__global__ __launch_bounds__(512) void fill_kernel(
    const int* __restrict__ src, const int* __restrict__ dst,
    const int* __restrict__ hist2d, const int* __restrict__ binOff,
    int* __restrict__ bucket, int nbin, int n_edges) {
    __shared__ int cur[MAXNODE];
    int tid = threadIdx.x, fb = blockIdx.x;
    for (int i = tid; i < nbin; i += 512)
        cur[i] = hist2d[(size_t)fb * nbin + i] + binOff[i];
    __syncthreads();
    int chunk = (n_edges + FB - 1) / FB;
    int e0 = fb * chunk, e1 = min(e0 + chunk, n_edges);
    int a0 = min(e1, (e0 + 3) & ~3);
    for (int e = e0 + tid; e < a0; e += 512) {
        int pos = atomicAdd(&cur[dst[e]], 1);
        bucket[pos] = src[e];
    }
    const int4* d4 = (const int4*)dst;
    const int4* s4 = (const int4*)src;
    int vs = a0 >> 2, ve = e1 >> 2;
    for (int i = vs + tid; i < ve; i += 512) {
        int4 d = d4[i];
        int4 s = s4[i];
        int p0 = atomicAdd(&cur[d.x], 1);
        int p1 = atomicAdd(&cur[d.y], 1);
        int p2 = atomicAdd(&cur[d.z], 1);
        int p3 = atomicAdd(&cur[d.w], 1);
        bucket[p0] = s.x; bucket[p1] = s.y; bucket[p2] = s.z; bucket[p3] = s.w;
    }
    for (int e = (ve << 2) + tid; e < e1; e += 512)
        if (e >= a0) {
            int pos = atomicAdd(&cur[dst[e]], 1);
            bucket[pos] = src[e];
        }
}

// ---------- gather: wave-per-node, 8-edge ILP; h0[n] = x[n] + sum x[src] ----------
__global__ __launch_bounds__(256) void gather_kernel(
    const float* __restrict__ x, const int* __restrict__ bucket,
    const int* __restrict__ binOff, float* __restrict__ h0, int n_nodes) {
    int gw = (blockIdx.x * blockDim.x + threadIdx.x) >> 6;
    int lane = threadIdx.x & 63;
    if (gw >= n_nodes) return;
    const float2* x2 = (const float2*)x;
    float2 acc = x2[(size_t)gw * 64 + lane];
    int j = binOff[gw], end = binOff[gw + 1];
    for (; j + 8 <= end; j += 8) {
        int s0 = bucket[j],     s1 = bucket[j + 1], s2 = bucket[j + 2], s3 = bucket[j + 3];
        int s4 = bucket[j + 4], s5 = bucket[j + 5], s6 = bucket[j + 6], s7 = bucket[j + 7];
        float2 v0 = x2[(size_t)s0 * 64 + lane];
        float2 v1 = x2[(size_t)s1 * 64 + lane];
        float2 v2 = x2[(size_t)s2 * 64 + lane];
        float2 v3 = x2[(size_t)s3 * 64 + lane];
        float2 v4 = x2[(size_t)s4 * 64 + lane];
        float2 v5 = x2[(size_t)s5 * 64 + lane];
        float2 v6 = x2[(size_t)s6 * 64 + lane];
        float2 v7 = x2[(size_t)s7 * 64 + lane];
        acc.x += ((v0.x + v1.x) + (v2.x + v3.x)) + ((v4.x + v5.x) + (v6.x + v7.x));
        acc.y += ((v0.y + v1.y) + (v2.y + v3.y)) + ((v4.y + v5.y) + (v6.y + v7.y));
    }
    for (; j < end; ++j) {
        int s = bucket[j];
        float2 v = x2[(size_t)s * 64 + lane];
        acc.x += v.x;
        acc.y += v.y;
    }
    ((float2*)h0)[(size_t)gw * 64 + lane] = acc;
}

// ---------- fallback: atomic scatter ----------
__global__ void edge_scatter_kernel(const int* __restrict__ ei, const float* __restrict__ x,
                                    float* __restrict__ h0, int n_edges) {
    int gtid = blockIdx.x * blockDim.x + threadIdx.x;
    int wid = gtid >> 6;
    int lane = threadIdx.x & 63;
    int nw = (gridDim.x * blockDim.x) >> 6;
    const int* srcs = ei;
    const int* dsts = ei + n_edges;
    for (int e = wid; e < n_edges; e += nw) {
        int s = srcs[e];
        int d = dsts[e];
        atomicAdd(&h0[d * NF + lane], x[s * NF + lane]);
        atomicAdd(&h0[d * NF + 64 + lane], x[s * NF + 64 + lane]);
    }
}

// ---------- GEMM1: out = relu(h0 @ W1t + b1), fused BN col stats (R3-proven structure) ------
__global__ __launch_bounds__(256, 1) void gemm1_kernel(
    const float* __restrict__ H, const float* __restrict__ Wt,
    const float* __restrict__ bias, float* __restrict__ O,
    float* __restrict__ colsum, float* __restrict__ colsumsq, int n_rows) {
    __shared__ float Hl[64][128];
    __shared__ float Wl[128][132];
    int tid = threadIdx.x;
    int m0 = blockIdx.x * 64;

    const float4* Wt4 = (const float4*)Wt;
    for (int j = tid; j < 4096; j += 256) {
        int k = j >> 5, c4 = (j & 31) << 2;
        float4 w = Wt4[j];
        *(float4*)&Wl[k][c4] = w;
    }
    const float4* H4 = (const float4*)H;
    for (int j = tid; j < 2048; j += 256) {
        int r = j >> 5, k4 = j & 31;
        int gr = m0 + r;
        float4 h = (gr < n_rows) ? H4[(size_t)gr * 32 + k4] : make_float4(0.f, 0.f, 0.f, 0.f);
        *(float4*)&Hl[r][k4 << 2] = h;
    }
    __syncthreads();

    int tx = tid & 31, ty = tid >> 5;
    int rb = ty * 8, cb = tx * 4;
    float acc[8][4] = {};

    for (int k = 0; k < 128; k += 4) {
        float wv[4][4];
#pragma unroll
        for (int kk = 0; kk < 4; ++kk) {
            float4 t = *(const float4*)&Wl[k + kk][cb];
            wv[kk][0] = t.x; wv[kk][1] = t.y; wv[kk][2] = t.z; wv[kk][3] = t.w;
        }
#pragma unroll
        for (int i = 0; i < 8; ++i) {
            float4 h = *(const float4*)&Hl[rb + i][k];
            float hf[4] = {h.x, h.y, h.z, h.w};
#pragma unroll
            for (int kk = 0; kk < 4; ++kk)
#pragma unroll
                for (int j = 0; j < 4; ++j)
                    acc[i][j] = fmaf(hf[kk], wv[kk][j], acc[i][j]);
        }
    }

    float bv[4];
#pragma unroll
    for (int j = 0; j < 4; ++j) bv[j] = bias[cb + j];

    float s[4] = {0.f, 0.f, 0.f, 0.f}, q[4] = {0.f, 0.f, 0.f, 0.f};
#pragma unroll
    for (int i = 0; i < 8; ++i) {
        int gr = m0 + rb + i;
        if (gr < n_rows) {
            float o[4];
#pragma unroll
            for (int j = 0; j < 4; ++j) {
                float v = acc[i][j] + bv[j];
                v = fmaxf(v, 0.f);
                o[j] = v;
                s[j] += v;
                q[j] = fmaf(v, v, q[j]);
            }
            *(float4*)&O[(size_t)gr * NF + cb] = make_float4(o[0], o[1], o[2], o[3]);
        }
    }

    __syncthreads();  // done with Hl; reuse as BN reduce scratch
    float* sS = &Hl[0][0];
    float* sQ = &Hl[16][0];
#pragma unroll
    for (int j = 0; j < 4; ++j) {
        sS[ty * 128 + cb + j] = s[j];
        sQ[ty * 128 + cb + j] = q[j];
    }
    __syncthreads();
    if (tid < 128) {
        float ts = 0.f, tq = 0.f;
#pragma unroll
        for (int g = 0; g < 8; ++g) {
            ts += sS[g * 128 + tid];
            tq += sQ[g * 128 + tid];
        }
        atomicAdd(&colsum[tid], ts);
        atomicAdd(&colsumsq[tid], tq);
    }
}

// ---------- GEMM2 with fused BN fold: O = h1 @ (diag? folded W2)^T + b2' (in-place safe) ----
__global__ __launch_bounds__(256, 1) void gemm2_fold_kernel(
    const float* __restrict__ H, const float* __restrict__ W2,
    const float* __restrict__ b2, const float* __restrict__ gamma,
    const float* __restrict__ beta, const float* __restrict__ colsum,
    const float* __restrict__ colsumsq, const float* __restrict__ inv_sigma,
    float* __restrict__ O, int n_rows, float inv_n) {
    __shared__ float Hl[64][128];
    __shared__ float Wl[128][132];
    __shared__ float a_s[128], c_s[128], bsh[128];
    int tid = threadIdx.x;
    int m0 = blockIdx.x * 64;

    if (tid < 128) {
        float mu = colsum[tid] * inv_n;
        float var = colsumsq[tid] * inv_n - mu * mu;
        float ai = gamma[tid] / sqrtf(var + 1e-5f);
        a_s[tid] = ai;
        c_s[tid] = beta[tid] - ai * mu;
        bsh[tid] = 0.f;
    }
    const float4* H4 = (const float4*)H;
    for (int j = tid; j < 2048; j += 256) {
        int r = j >> 5, k4 = j & 31;
        int gr = m0 + r;
        float4 h = (gr < n_rows) ? H4[(size_t)gr * 32 + k4] : make_float4(0.f, 0.f, 0.f, 0.f);
        *(float4*)&Hl[r][k4 << 2] = h;
    }
    __syncthreads();

    // stage folded W: Wl[k][j] = W2[j][k]*is2*a[k]; bsh[j] += W2[j][k]*is2*c[k]
    float is2 = inv_sigma[1];
    const float4* W4 = (const float4*)W2;
    for (int idx = tid; idx < 4096; idx += 256) {
        int j = idx & 127, k4 = idx >> 7, k = k4 << 2;
        float4 w = W4[j * 32 + k4];  // W2[j][k..k+3]
        w.x *= is2; w.y *= is2; w.z *= is2; w.w *= is2;
        Wl[k][j]     = w.x * a_s[k];
        Wl[k + 1][j] = w.y * a_s[k + 1];
        Wl[k + 2][j] = w.z * a_s[k + 2];
        Wl[k + 3][j] = w.w * a_s[k + 3];
        float pb = w.x * c_s[k] + w.y * c_s[k + 1] + w.z * c_s[k + 2] + w.w * c_s[k + 3];
        atomicAdd(&bsh[j], pb);
    }
    __syncthreads();

    int tx = tid & 31, ty = tid >> 5;
    int rb = ty * 8, cb = tx * 4;
    float acc[8][4] = {};

    for (int k = 0; k < 128; k += 4) {
        float wv[4][4];
#pragma unroll
        for (int kk = 0; kk < 4; ++kk) {
            float4 t = *(const float4*)&Wl[k + kk][cb];
            wv[kk][0] = t.x; wv[kk][1] = t.y; wv[kk][2] = t.z; wv[kk][3] = t.w;
        }
#pragma unroll
        for (int i = 0; i < 8; ++i) {
            float4 h = *(const float4*)&Hl[rb + i][k];
            float hf[4] = {h.x, h.y, h.z, h.w};
#pragma unroll
            for (int kk = 0; kk < 4; ++kk)
#pragma unroll
                for (int j = 0; j < 4; ++j)
                    acc[i][j] = fmaf(hf[kk], wv[kk][j], acc[i][j]);
        }
    }

    float bv[4];
#pragma unroll
    for (int j = 0; j < 4; ++j) bv[j] = b2[cb + j] + bsh[cb + j];

#pragma unroll
    for (int i = 0; i < 8; ++i) {
        int gr = m0 + rb + i;
        if (gr < n_rows) {
            float o[4];
#pragma unroll
            for (int j = 0; j < 4; ++j) o[j] = acc[i][j] + bv[j];
            *(float4*)&O[(size_t)gr * NF + cb] = make_float4(o[0], o[1], o[2], o[3]);
        }
    }
}

extern "C" void kernel_launch(void* const* d_in, const int* in_sizes, int n_in,
                              void* d_out, int out_size, void* d_ws, size_t ws_size,
                              hipStream_t stream) {
    const float* x     = (const float*)d_in[0];
    const int*   ei    = (const int*)d_in[1];
    const float* W1    = (const float*)d_in[2];
    const float* b1    = (const float*)d_in[3];
    const float* u1    = (const float*)d_in[4];
    const float* gamma = (const float*)d_in[5];
    const float* beta  = (const float*)d_in[6];
    const float* W2    = (const float*)d_in[7];
    const float* b2    = (const float*)d_in[8];
    const float* u2    = (const float*)d_in[9];
    float* out = (float*)d_out;

    int n_nodes = in_sizes[0] / NF;
    int n_edges = in_sizes[1] / 2;
    int nbin = n_nodes;

    float* ws        = (float*)d_ws;
    float* inv_sigma = ws;                // 4
    float* colsum    = ws + 4;            // 128
    float* colsumsq  = colsum + 128;      // 128
    float* W1t       = colsumsq + 128;    // 16384
    int*   binOff    = (int*)(W1t + 16384);            // nbin+1
    int*   bucket    = binOff + nbin + 1;              // n_edges
    float* h0        = (float*)(bucket + n_edges);     // n_nodes*128
    int*   hist2d    = (int*)h0;                       // FB*nbin (dead before gather writes h0)

    size_t fixed = (4 + 256 + 16384) * sizeof(float);
    size_t need  = fixed + ((size_t)nbin + 1 + n_edges) * sizeof(int)
                 + (size_t)n_nodes * NF * sizeof(float);
    bool fused = (n_nodes <= MAXNODE) && (ws_size >= need)
               && ((size_t)FB * nbin <= (size_t)n_nodes * NF);

    if (fused) {
        // power iteration (blocks 0,1; zeros colsum, emits W1t) + node hist (blocks 2..FB+1)
        power_hist_kernel<<<2 + FB, 512, 0, stream>>>(
            W1, u1, W2, u2, ei + n_edges, n_edges, hist2d, nbin, inv_sigma, W1t, colsum);
        scanA_kernel<<<(nbin + 1023) / 1024, 1024, 0, stream>>>(hist2d, binOff, nbin);
        scanB_kernel<<<1, 1024, 0, stream>>>(binOff, nbin);
        fill_kernel<<<FB, 512, 0, stream>>>(ei, ei + n_edges, hist2d, binOff, bucket,
                                            nbin, n_edges);
        gather_kernel<<<(n_nodes * 64 + 255) / 256, 256, 0, stream>>>(
            x, bucket, binOff, h0, n_nodes);
    } else {
        power_hist_kernel<<<2, 512, 0, stream>>>(
            W1, u1, W2, u2, ei + n_edges, n_edges, nullptr, nbin, inv_sigma, W1t, colsum);
        hipMemcpyAsync(h0, x, (size_t)n_nodes * NF * sizeof(float),
                       hipMemcpyDeviceToDevice, stream);
        edge_scatter_kernel<<<2048, 256, 0, stream>>>(ei, x, h0, n_edges);
    }

    int gemm_blocks = (n_nodes + 63) / 64;

    // h1 = relu(h0 @ W1sn^T + b1) -> d_out, fused BN col stats
    gemm1_kernel<<<gemm_blocks, 256, 0, stream>>>(h0, W1t, b1, out, colsum, colsumsq, n_nodes);

    // out = h1 @ W2fold^T + b2'  (fold computed in-kernel; in-place safe per block)
    gemm2_fold_kernel<<<gemm_blocks, 256, 0, stream>>>(
        out, W2, b2, gamma, beta, colsum, colsumsq, inv_sigma, out, n_nodes,
        1.0f / (float)n_nodes);
}

// Round 10
// 112.838 us; speedup vs baseline: 8.5958x; 1.1181x over previous
//
#include <hip/hip_runtime.h>

#define NF 128
#define FB 128           // hist/fill partition chunks
#define CB 64            // cast blocks
#define MAXNODE 10240    // LDS cursor capacity (ints)

__device__ __forceinline__ unsigned short f2bf(float f) {  // RNE bf16
    unsigned int u = __float_as_uint(f);
    unsigned int r = u + 0x7FFFu + ((u >> 16) & 1u);
    return (unsigned short)(r >> 16);
}

// ---- power iteration (blocks 0,1) + node histogram (2..FB+1) + x->bf16 cast (rest) ----
__global__ __launch_bounds__(512) void power_hist_kernel(
    const float* __restrict__ W1, const float* __restrict__ u1,
    const float* __restrict__ W2, const float* __restrict__ u2,
    const int* __restrict__ dst, int n_edges,
    int* __restrict__ hist2d, int nbin,
    const float* __restrict__ x, unsigned short* __restrict__ xb, int n_x4,
    float* __restrict__ inv_sigma, float* __restrict__ W1t,
    float* __restrict__ colzero) {
    __shared__ float Wl[128][129];
    __shared__ float us[128], vv[128], part[4][128], red[128];
    __shared__ int hist[MAXNODE];
    int tid = threadIdx.x;

    if (blockIdx.x >= 2 + FB) {  // cast x -> bf16 (RNE)
        int cb = blockIdx.x - 2 - FB;
        const float4* x4 = (const float4*)x;
        ushort4* xb4 = (ushort4*)xb;
        for (int i = cb * 512 + tid; i < n_x4; i += CB * 512) {
            float4 v = x4[i];
            ushort4 o;
            o.x = f2bf(v.x); o.y = f2bf(v.y); o.z = f2bf(v.z); o.w = f2bf(v.w);
            xb4[i] = o;
        }
        return;
    }
    if (blockIdx.x >= 2) {  // histogram chunk
        int fb = blockIdx.x - 2;
        for (int i = tid; i < nbin; i += 512) hist[i] = 0;
        __syncthreads();
        int chunk = (n_edges + FB - 1) / FB;
        int e0 = fb * chunk, e1 = min(e0 + chunk, n_edges);
        int a0 = min(e1, (e0 + 3) & ~3);
        for (int e = e0 + tid; e < a0; e += 512) atomicAdd(&hist[dst[e]], 1);
        const int4* d4 = (const int4*)dst;
        int vs = a0 >> 2, ve = e1 >> 2;
        for (int i = vs + tid; i < ve; i += 512) {
            int4 d = d4[i];
            atomicAdd(&hist[d.x], 1);
            atomicAdd(&hist[d.y], 1);
            atomicAdd(&hist[d.z], 1);
            atomicAdd(&hist[d.w], 1);
        }
        for (int e = (ve << 2) + tid; e < e1; e += 512)
            if (e >= a0) atomicAdd(&hist[dst[e]], 1);
        __syncthreads();
        for (int i = tid; i < nbin; i += 512) hist2d[(size_t)fb * nbin + i] = hist[i];
        return;
    }

    const float* W = blockIdx.x ? W2 : W1;
    const float* u = blockIdx.x ? u2 : u1;
    const float4* W4 = (const float4*)W;
    for (int j = tid; j < 4096; j += 512) {
        float4 w = W4[j];
        int r = j >> 5, c0 = (j & 31) << 2;
        Wl[r][c0] = w.x; Wl[r][c0 + 1] = w.y; Wl[r][c0 + 2] = w.z; Wl[r][c0 + 3] = w.w;
    }
    if (tid < 128) us[tid] = u[tid];
    if (blockIdx.x == 0 && tid >= 256 && tid < 512) colzero[tid - 256] = 0.f;
    __syncthreads();

    int c = tid & 127, sl = tid >> 7;
    float acc = 0.f;
#pragma unroll
    for (int j = 0; j < 32; ++j) acc = fmaf(Wl[sl * 32 + j][c], us[sl * 32 + j], acc);
    part[sl][c] = acc;
    __syncthreads();
    if (tid < 128) {
        float v = part[0][tid] + part[1][tid] + part[2][tid] + part[3][tid];
        vv[tid] = v;
        red[tid] = v * v;
    }
    __syncthreads();
    for (int s = 64; s > 0; s >>= 1) { if (tid < s) red[tid] += red[tid + s]; __syncthreads(); }
    float nv = sqrtf(red[0]) + 1e-12f;
    __syncthreads();
    if (tid < 128) vv[tid] = vv[tid] / nv;
    __syncthreads();

    float t = 0.f;
#pragma unroll
    for (int k = 0; k < 32; ++k) t = fmaf(Wl[c][sl * 32 + k], vv[sl * 32 + k], t);
    part[sl][c] = t;
    __syncthreads();
    if (tid < 128) {
        float tv = part[0][tid] + part[1][tid] + part[2][tid] + part[3][tid];
        red[tid] = tv * tv;
    }
    __syncthreads();
    for (int s = 64; s > 0; s >>= 1) { if (tid < s) red[tid] += red[tid + s]; __syncthreads(); }
    float tt = red[0];
    float is = (sqrtf(tt) + 1e-12f) / tt;
    if (tid == 0) inv_sigma[blockIdx.x] = is;
    if (blockIdx.x == 0) {
        for (int idx = tid; idx < 16384; idx += 512) {
            int k = idx >> 7, j = idx & 127;
            W1t[idx] = Wl[j][k] * is;  // W1t[k][j]
        }
    }
}

// ---- scanA: thread-per-node exclusive prefix over fb; binOff[n] = node total ----
__global__ void scanA_kernel(int* __restrict__ hist2d, int* __restrict__ binOff, int nbin) {
    int bin = blockIdx.x * 1024 + threadIdx.x;
    if (bin >= nbin) return;
    int run = 0;
#pragma unroll 4
    for (int fb = 0; fb < FB; ++fb) {
        int v = hist2d[(size_t)fb * nbin + bin];
        hist2d[(size_t)fb * nbin + bin] = run;
        run += v;
    }
    binOff[bin] = run;
}

// ---- scanB: shuffle-based tiled exclusive scan of binOff; binOff[nbin] = total ----
__global__ __launch_bounds__(1024) void scanB_kernel(int* __restrict__ binOff, int nbin) {
    __shared__ int wsum[16], wexcl[16];
    __shared__ int carry_s;
    int tid = threadIdx.x, lane = tid & 63, wv = tid >> 6;
    if (tid == 0) carry_s = 0;
    __syncthreads();
    int nr = (nbin + 1023) >> 10;
    for (int r = 0; r < nr; ++r) {
        int i = (r << 10) + tid;
        int v = (i < nbin) ? binOff[i] : 0;
        int inc = v;
        for (int off = 1; off < 64; off <<= 1) {
            int t = __shfl_up(inc, off);
            if (lane >= off) inc += t;
        }
        if (lane == 63) wsum[wv] = inc;
        __syncthreads();
        if (wv == 0) {
            int s = (lane < 16) ? wsum[lane] : 0;
            int si = s;
            for (int off = 1; off < 16; off <<= 1) {
                int t = __shfl_up(si, off);
                if (lane >= off) si += t;
            }
            if (lane < 16) wexcl[lane] = si - s;
        }
        __syncthreads();
        int excl = inc - v + wexcl[wv] + carry_s;
        if (i < nbin) binOff[i] = excl;
        __syncthreads();
        if (tid == 1023) carry_s += wexcl[15] + wsum[15];
        __syncthreads();
    }
    if (threadIdx.x == 0) binOff[nbin] = carry_s;
}

// ---- fill: LDS cursors, scatter src ids into node buckets ----
__global__ __launch_bounds__(512) void fill_kernel(
    const int* __restrict__ src, const int* __restrict__ dst,
    const int* __restrict__ hist2d, const int* __restrict__ binOff,
    int* __restrict__ bucket, int nbin, int n_edges) {
    __shared__ int cur[MAXNODE];
    int tid = threadIdx.x, fb = blockIdx.x;
    for (int i = tid; i < nbin; i += 512)
        cur[i] = hist2d[(size_t)fb * nbin + i] + binOff[i];
    __syncthreads();
    int chunk = (n_edges + FB - 1) / FB;
    int e0 = fb * chunk, e1 = min(e0 + chunk, n_edges);
    int a0 = min(e1, (e0 + 3) & ~3);
    for (int e = e0 + tid; e < a0; e += 512) {
        int pos = atomicAdd(&cur[dst[e]], 1);
        bucket[pos] = src[e];
    }
    const int4* d4 = (const int4*)dst;
    const int4* s4 = (const int4*)src;
    int vs = a0 >> 2, ve = e1 >> 2;
    for (int i = vs + tid; i < ve; i += 512) {
        int4 d = d4[i];
        int4 s = s4[i];
        int p0 = atomicAdd(&cur[d.x], 1);
        int p1 = atomicAdd(&cur[d.y], 1);
        int p2 = atomicAdd(&cur[d.z], 1);
        int p3 = atomicAdd(&cur[d.w], 1);
        bucket[p0] = s.x; bucket[p1] = s.y; bucket[p2] = s.z; bucket[p3] = s.w;
    }
    for (int e = (ve << 2) + tid; e < e1; e += 512)
        if (e >= a0) {
            int pos = atomicAdd(&cur[dst[e]], 1);
            bucket[pos] = src[e];
        }
}

// ---- gather (bf16 source): wave-per-node, 8-edge ILP; h0 = x + sum x[src] (f32 acc) ----
__global__ __launch_bounds__(256) void gather_kernel(
    const unsigned short* __restrict__ xb, const int* __restrict__ bucket,
    const int* __restrict__ binOff, float* __restrict__ h0, int n_nodes) {
    int gw = (blockIdx.x * blockDim.x + threadIdx.x) >> 6;
    int lane = threadIdx.x & 63;
    if (gw >= n_nodes) return;
    const unsigned int* xu = (const unsigned int*)xb;  // 2 bf16 per uint; row = 64 uints
    unsigned int u0 = xu[(size_t)gw * 64 + lane];
    float2 acc;
    acc.x = __uint_as_float(u0 << 16);
    acc.y = __uint_as_float(u0 & 0xFFFF0000u);
    int j = binOff[gw], end = binOff[gw + 1];
    for (; j + 8 <= end; j += 8) {
        int s0 = bucket[j],     s1 = bucket[j + 1], s2 = bucket[j + 2], s3 = bucket[j + 3];
        int s4 = bucket[j + 4], s5 = bucket[j + 5], s6 = bucket[j + 6], s7 = bucket[j + 7];
        unsigned int v0 = xu[(size_t)s0 * 64 + lane];
        unsigned int v1 = xu[(size_t)s1 * 64 + lane];
        unsigned int v2 = xu[(size_t)s2 * 64 + lane];
        unsigned int v3 = xu[(size_t)s3 * 64 + lane];
        unsigned int v4 = xu[(size_t)s4 * 64 + lane];
        unsigned int v5 = xu[(size_t)s5 * 64 + lane];
        unsigned int v6 = xu[(size_t)s6 * 64 + lane];
        unsigned int v7 = xu[(size_t)s7 * 64 + lane];
        acc.x += __uint_as_float(v0 << 16) + __uint_as_float(v1 << 16)
               + __uint_as_float(v2 << 16) + __uint_as_float(v3 << 16)
               + __uint_as_float(v4 << 16) + __uint_as_float(v5 << 16)
               + __uint_as_float(v6 << 16) + __uint_as_float(v7 << 16);
        acc.y += __uint_as_float(v0 & 0xFFFF0000u) + __uint_as_float(v1 & 0xFFFF0000u)
               + __uint_as_float(v2 & 0xFFFF0000u) + __uint_as_float(v3 & 0xFFFF0000u)
               + __uint_as_float(v4 & 0xFFFF0000u) + __uint_as_float(v5 & 0xFFFF0000u)
               + __uint_as_float(v6 & 0xFFFF0000u) + __uint_as_float(v7 & 0xFFFF0000u);
    }
    for (; j < end; ++j) {
        unsigned int v = xu[(size_t)bucket[j] * 64 + lane];
        acc.x += __uint_as_float(v << 16);
        acc.y += __uint_as_float(v & 0xFFFF0000u);
    }
    ((float2*)h0)[(size_t)gw * 64 + lane] = acc;
}

// ---- fallback: atomic scatter (f32) ----
__global__ void edge_scatter_kernel(const int* __restrict__ ei, const float* __restrict__ x,
                                    float* __restrict__ h0, int n_edges) {
    int gtid = blockIdx.x * blockDim.x + threadIdx.x;
    int wid = gtid >> 6;
    int lane = threadIdx.x & 63;
    int nw = (gridDim.x * blockDim.x) >> 6;
    const int* srcs = ei;
    const int* dsts = ei + n_edges;
    for (int e = wid; e < n_edges; e += nw) {
        int s = srcs[e];
        int d = dsts[e];
        atomicAdd(&h0[d * NF + lane], x[s * NF + lane]);
        atomicAdd(&h0[d * NF + 64 + lane], x[s * NF + 64 + lane]);
    }
}

// ---- GEMM: O = act(H @ Wt + bias); Wt [k][c] in GLOBAL (L1/L2 broadcast), H in LDS ----
// 32KB LDS + <=128 VGPR -> 4 blocks/CU. Thread (ty,tx): rows ty*8..+7, cols tx*4..+3.
template <bool RELU, bool BNACC>
__global__ __launch_bounds__(256, 4) void gemm_kernel(
    const float* __restrict__ H, const float* __restrict__ Wt,
    const float* __restrict__ bias, float* __restrict__ O,
    float* __restrict__ colsum, float* __restrict__ colsumsq, int n_rows) {
    __shared__ float Hl[64][128];  // 32 KB
    int tid = threadIdx.x;
    int m0 = blockIdx.x * 64;

    const float4* H4 = (const float4*)H;
    for (int j = tid; j < 2048; j += 256) {
        int r = j >> 5, k4 = j & 31;
        int gr = m0 + r;
        float4 h = (gr < n_rows) ? H4[(size_t)gr * 32 + k4] : make_float4(0.f, 0.f, 0.f, 0.f);
        *(float4*)&Hl[r][k4 << 2] = h;
    }
    __syncthreads();

    int tx = tid & 31, ty = tid >> 5;
    int rb = ty * 8, cb = tx * 4;
    float acc[8][4] = {};
    const float4* Wt4 = (const float4*)Wt;

#pragma unroll 2
    for (int k = 0; k < 128; k += 4) {
        float4 w0 = Wt4[(k + 0) * 32 + tx];   // same addr across ty-waves & blocks -> L1/L2 hot
        float4 w1 = Wt4[(k + 1) * 32 + tx];
        float4 w2 = Wt4[(k + 2) * 32 + tx];
        float4 w3 = Wt4[(k + 3) * 32 + tx];
        float wv[4][4] = {{w0.x, w0.y, w0.z, w0.w}, {w1.x, w1.y, w1.z, w1.w},
                          {w2.x, w2.y, w2.z, w2.w}, {w3.x, w3.y, w3.z, w3.w}};
#pragma unroll
        for (int i = 0; i < 8; ++i) {
            float4 h = *(const float4*)&Hl[rb + i][k];
            float hf[4] = {h.x, h.y, h.z, h.w};
#pragma unroll
            for (int kk = 0; kk < 4; ++kk)
#pragma unroll
                for (int j = 0; j < 4; ++j)
                    acc[i][j] = fmaf(hf[kk], wv[kk][j], acc[i][j]);
        }
    }

    float bv[4];
#pragma unroll
    for (int j = 0; j < 4; ++j) bv[j] = bias[cb + j];

    float s[4] = {0.f, 0.f, 0.f, 0.f}, q[4] = {0.f, 0.f, 0.f, 0.f};
#pragma unroll
    for (int i = 0; i < 8; ++i) {
        int gr = m0 + rb + i;
        if (gr < n_rows) {
            float o[4];
#pragma unroll
            for (int j = 0; j < 4; ++j) {
                float v = acc[i][j] + bv[j];
                if (RELU) v = fmaxf(v, 0.f);
                o[j] = v;
                if (BNACC) { s[j] += v; q[j] = fmaf(v, v, q[j]); }
            }
            *(float4*)&O[(size_t)gr * NF + cb] = make_float4(o[0], o[1], o[2], o[3]);
        }
    }

    if (BNACC) {
        __syncthreads();  // done with Hl; reuse as reduce scratch
        float* sS = &Hl[0][0];
        float* sQ = &Hl[16][0];
#pragma unroll
        for (int j = 0; j < 4; ++j) {
            sS[ty * 128 + cb + j] = s[j];
            sQ[ty * 128 + cb + j] = q[j];
        }
        __syncthreads();
        if (tid < 128) {
            float ts = 0.f, tq = 0.f;
#pragma unroll
            for (int g = 0; g < 8; ++g) {
                ts += sS[g * 128 + tid];
                tq += sQ[g * 128 + tid];
            }
            atomicAdd(&colsum[tid], ts);
            atomicAdd(&colsumsq[tid], tq);
        }
    }
}

// ---- fold BN into W2', emit TRANSPOSED W2pt[k][j], b2p ----
__global__ void fold_kernel(const float* __restrict__ W2, const float* __restrict__ b2,
                            const float* __restrict__ gamma, const float* __restrict__ beta,
                            const float* __restrict__ colsum, const float* __restrict__ colsumsq,
                            const float* __restrict__ inv_sigma, float* __restrict__ W2pt,
                            float* __restrict__ b2p, float inv_n) {
    __shared__ float a[128], cc[128], red[128];
    int k = threadIdx.x;
    int j = blockIdx.x;
    float mu = colsum[k] * inv_n;
    float var = colsumsq[k] * inv_n - mu * mu;
    float ai = gamma[k] / sqrtf(var + 1e-5f);
    a[k] = ai;
    cc[k] = beta[k] - ai * mu;
    __syncthreads();
    float is2 = inv_sigma[1];
    float wv = W2[j * 128 + k] * is2;
    W2pt[k * 128 + j] = wv * a[k];
    red[k] = wv * cc[k];
    __syncthreads();
    for (int s = 64; s > 0; s >>= 1) { if (k < s) red[k] += red[k + s]; __syncthreads(); }
    if (k == 0) b2p[j] = b2[j] + red[0];
}

extern "C" void kernel_launch(void* const* d_in, const int* in_sizes, int n_in,
                              void* d_out, int out_size, void* d_ws, size_t ws_size,
                              hipStream_t stream) {
    const float* x     = (const float*)d_in[0];
    const int*   ei    = (const int*)d_in[1];
    const float* W1    = (const float*)d_in[2];
    const float* b1    = (const float*)d_in[3];
    const float* u1    = (const float*)d_in[4];
    const float* gamma = (const float*)d_in[5];
    const float* beta  = (const float*)d_in[6];
    const float* W2    = (const float*)d_in[7];
    const float* b2    = (const float*)d_in[8];
    const float* u2    = (const float*)d_in[9];
    float* out = (float*)d_out;

    int n_nodes = in_sizes[0] / NF;
    int n_edges = in_sizes[1] / 2;
    int nbin = n_nodes;
    int nbin_pad = (nbin + 1 + 3) & ~3;       // keep downstream 16B-aligned
    int nedge_pad = (n_edges + 3) & ~3;

    float* ws        = (float*)d_ws;
    float* inv_sigma = ws;                     // 4
    float* colsum    = ws + 4;                 // 128
    float* colsumsq  = colsum + 128;           // 128
    float* W1t       = colsumsq + 128;         // 16384
    float* W2pt      = W1t + 16384;            // 16384
    float* b2p       = W2pt + 16384;           // 128 (total 33156, 16B-aligned)
    int*   binOff    = (int*)(b2p + 128);      // nbin_pad
    int*   bucket    = binOff + nbin_pad;      // nedge_pad
    float* h0        = (float*)(bucket + nedge_pad);       // n_nodes*128 (16B-aligned)
    unsigned short* xb = (unsigned short*)(h0 + (size_t)n_nodes * NF);  // n_nodes*128 bf16
    int*   hist2d    = (int*)h0;               // FB*nbin aliased (dead before gather)

    size_t need = (size_t)(33156 + nbin_pad + nedge_pad) * 4
                + (size_t)n_nodes * NF * 4 + (size_t)n_nodes * NF * 2;
    bool fused = (n_nodes <= MAXNODE) && (ws_size >= need)
               && ((size_t)FB * nbin <= (size_t)n_nodes * NF);

    int n_x4 = n_nodes * 32;  // float4 count of x

    if (fused) {
        // blocks 0,1: power iter (zeros colsum, emits W1t); 2..FB+1: hist; rest: cast
        power_hist_kernel<<<2 + FB + CB, 512, 0, stream>>>(
            W1, u1, W2, u2, ei + n_edges, n_edges, hist2d, nbin,
            x, xb, n_x4, inv_sigma, W1t, colsum);
        scanA_kernel<<<(nbin + 1023) / 1024, 1024, 0, stream>>>(hist2d, binOff, nbin);
        scanB_kernel<<<1, 1024, 0, stream>>>(binOff, nbin);
        fill_kernel<<<FB, 512, 0, stream>>>(ei, ei + n_edges, hist2d, binOff, bucket,
                                            nbin, n_edges);
        gather_kernel<<<(n_nodes * 64 + 255) / 256, 256, 0, stream>>>(
            xb, bucket, binOff, h0, n_nodes);
    } else {
        power_hist_kernel<<<2, 512, 0, stream>>>(
            W1, u1, W2, u2, ei + n_edges, n_edges, nullptr, nbin,
            x, xb, 0, inv_sigma, W1t, colsum);
        hipMemcpyAsync(h0, x, (size_t)n_nodes * NF * sizeof(float),
                       hipMemcpyDeviceToDevice, stream);
        edge_scatter_kernel<<<2048, 256, 0, stream>>>(ei, x, h0, n_edges);
    }

    int gemm_blocks = (n_nodes + 63) / 64;

    // h1 = relu(h0 @ W1sn^T + b1) -> d_out, fused BN col stats
    gemm_kernel<true, true><<<gemm_blocks, 256, 0, stream>>>(
        h0, W1t, b1, out, colsum, colsumsq, n_nodes);

    fold_kernel<<<128, 128, 0, stream>>>(W2, b2, gamma, beta, colsum, colsumsq,
                                         inv_sigma, W2pt, b2p, 1.0f / (float)n_nodes);

    // out = h1 @ W2p^T + b2p  (in-place: block reads only its own tile rows)
    gemm_kernel<false, false><<<gemm_blocks, 256, 0, stream>>>(
        out, W2pt, b2p, out, nullptr, nullptr, n_nodes);
}